// Round 10
// baseline (294.755 us; speedup 1.0000x reference)
//
#include <hip/hip_runtime.h>
#include <math.h>

#define SEQL 4096
#define L2E 1.44269504088896340736f

#if defined(__has_builtin)
#if __has_builtin(__builtin_amdgcn_exp2f)
#define FAST_EXP2(x) __builtin_amdgcn_exp2f(x)
#endif
#endif
#ifndef FAST_EXP2
#define FAST_EXP2(x) exp2f(x)
#endif

__device__ __forceinline__ float sigmoid_f(float x){ return 1.0f/(1.0f+expf(-x)); }

// ---------------- conv 3x3, pad 1, 64x64 image (v5: shfl-conv) --------------
// Wave = one output row (lanes = 64 columns) x COG channels. NO input LDS,
// NO barriers: per (ci,r) one coalesced global row load + 2 shfl for the
// left/right neighbors, then 3*COG fma with wave-uniform s_load weights.
// v1/v3/v4 were all LDS-staging-latency bound (VALUBusy <=12%, time ~ 1/waves);
// this removes that pipe entirely. 512 blocks = 2 blocks/CU = 8 waves/CU.
template<int CI, int CO, int COG, bool RELU, bool RES>
__global__ __launch_bounds__(256) void conv3x3_k(const float* __restrict__ in,
    const float* __restrict__ wgt, const float* __restrict__ bias,
    const float* __restrict__ res, float* __restrict__ out)
{
  const int tid  = threadIdx.x;
  const int lane = tid & 63;
  const int ty   = tid >> 6;                 // 0..3
  const int tyu  = __builtin_amdgcn_readfirstlane(ty);
  const int h0   = blockIdx.x;               // output row
  const int co0  = (blockIdx.y*4 + tyu)*COG; // wave's first output channel
  const int b    = blockIdx.z;

  float acc[COG];
  #pragma unroll
  for (int u=0;u<COG;++u) acc[u] = 0.0f;

  const float* inb = in + (size_t)b*CI*4096;

  #pragma unroll 2
  for (int ci=0; ci<CI; ++ci){
    const float* wb = wgt + ((size_t)co0*CI + ci)*9;
    #pragma unroll
    for (int r=0;r<3;++r){
      const int h = h0 - 1 + r;
      float v = 0.0f;
      if (h>=0 && h<64)
        v = inb[((size_t)ci*64 + h)*64 + lane];
      float vl = __shfl_up(v, 1);
      float vr = __shfl_down(v, 1);
      if (lane == 0)  vl = 0.0f;
      if (lane == 63) vr = 0.0f;
      #pragma unroll
      for (int u=0;u<COG;++u){
        const float* wp = wb + (size_t)u*CI*9 + r*3;
        acc[u] = fmaf(vl, wp[0], fmaf(v, wp[1], fmaf(vr, wp[2], acc[u])));
      }
    }
  }

  #pragma unroll
  for (int u=0;u<COG;++u){
    float s = acc[u] + bias[co0+u];
    size_t ob = ((size_t)(b*CO+co0+u)*64 + h0)*64 + lane;
    if constexpr (RES)  s += res[ob];
    if constexpr (RELU) s = fmaxf(s, 0.0f);
    out[ob] = s;
  }
}

// ---- fused mamba front + scan pass 1 (64-token tiles, 1024-thread blocks).
//      (R5 known-good: uniform weight s_loads, transposed scan LDS, coalesced
//      cA/cH [bd][chunk][n].)
__global__ __launch_bounds__(1024, 4) void mamba_in_k(const float* __restrict__ x2,
    const float* __restrict__ g, const float* __restrict__ be,
    const float* __restrict__ Wip, const float* __restrict__ cw,
    const float* __restrict__ cb, const float* __restrict__ Wxp,
    const float* __restrict__ Wdt, const float* __restrict__ bdt,
    const float* __restrict__ A_log,
    float* __restrict__ xm2, float* __restrict__ szb, float* __restrict__ dlt,
    float* __restrict__ Bm, float* __restrict__ Cm,
    float* __restrict__ cA, float* __restrict__ cH)
{
  __shared__ __align__(16) float xn[68][37];   // LN'd tokens; later aliased xbT[32][68]
  __shared__ __align__(16) float xm[64][68];   // in_proj xm half [d][t]; later dl[d][tok]
  __shared__ __align__(16) float xtT[64][68];  // silu(conv) TRANSPOSED [d][tok]
  __shared__ __align__(16) float xd[64][67];   // x_dbl [tok][j]
  float (*xbT)[68] = reinterpret_cast<float(*)[68]>(&xn[0][0]); // B [n][tok], aliases xn
  const int tid = threadIdx.x, lane = tid & 63, ty = tid >> 6;  // ty 0..15
  const int tyu = __builtin_amdgcn_readfirstlane(ty);
  const int bi = blockIdx.x >> 6;
  const int l0 = (blockIdx.x & 63) << 6;

  // ---- LayerNorm: 67 rows (64 + 3 halo), 8 lanes/row, shfl-tree reduce ----
  {
    const int row = tid >> 3, sub = tid & 7;
    if (row < 67){
      const int tok = l0 - 3 + row;
      const int c0 = sub << 2;
      if (tok >= 0){
        float4 f = *(const float4*)(x2 + (size_t)bi*131072 + (size_t)tok*32 + c0);
        float s = (f.x+f.y)+(f.z+f.w);
        s += __shfl_xor(s,1); s += __shfl_xor(s,2); s += __shfl_xor(s,4);
        const float mu = s * 0.03125f;
        float dx=f.x-mu, dy=f.y-mu, dz=f.z-mu, dw=f.w-mu;
        float q = (dx*dx+dy*dy)+(dz*dz+dw*dw);
        q += __shfl_xor(q,1); q += __shfl_xor(q,2); q += __shfl_xor(q,4);
        const float rstd = 1.0f/sqrtf(q*0.03125f + 1e-5f);
        float4 gv = *(const float4*)(g  + c0);
        float4 bv = *(const float4*)(be + c0);
        xn[row][c0+0] = dx*rstd*gv.x + bv.x;
        xn[row][c0+1] = dy*rstd*gv.y + bv.y;
        xn[row][c0+2] = dz*rstd*gv.z + bv.z;
        xn[row][c0+3] = dw*rstd*gv.w + bv.w;
      } else {
        xn[row][c0+0]=0.0f; xn[row][c0+1]=0.0f;
        xn[row][c0+2]=0.0f; xn[row][c0+3]=0.0f;
      }
    }
  }
  __syncthreads();

  // ---- in_proj ----
  if (ty < 8){
    const int d0 = tyu*8;
    float xvA[32];
    #pragma unroll
    for (int c=0;c<32;++c) xvA[c] = xn[lane][c];
    #pragma unroll
    for (int jj=0;jj<8;++jj){
      const float4* wr = (const float4*)(Wip + (d0+jj)*32);
      float a = 0.0f;
      #pragma unroll
      for (int c4=0;c4<8;++c4){
        float4 w = wr[c4];
        a = fmaf(xvA[c4*4+0], w.x, a);
        a = fmaf(xvA[c4*4+1], w.y, a);
        a = fmaf(xvA[c4*4+2], w.z, a);
        a = fmaf(xvA[c4*4+3], w.w, a);
      }
      xm[d0+jj][lane] = a;
    }
    if (lane < 3){
      float xvB[32];
      #pragma unroll
      for (int c=0;c<32;++c) xvB[c] = xn[64+lane][c];
      #pragma unroll
      for (int jj=0;jj<8;++jj){
        const float4* wr = (const float4*)(Wip + (d0+jj)*32);
        float a = 0.0f;
        #pragma unroll
        for (int c4=0;c4<8;++c4){
          float4 w = wr[c4];
          a = fmaf(xvB[c4*4+0], w.x, a);
          a = fmaf(xvB[c4*4+1], w.y, a);
          a = fmaf(xvB[c4*4+2], w.z, a);
          a = fmaf(xvB[c4*4+3], w.w, a);
        }
        xm[d0+jj][64+lane] = a;
      }
    }
  } else {
    const int d0z = (tyu-8)*8;
    float xvC[32];
    #pragma unroll
    for (int c=0;c<32;++c) xvC[c] = xn[lane+3][c];
    #pragma unroll
    for (int jj=0;jj<8;++jj){
      const float4* wr = (const float4*)(Wip + (64+d0z+jj)*32);
      float a = 0.0f;
      #pragma unroll
      for (int c4=0;c4<8;++c4){
        float4 w = wr[c4];
        a = fmaf(xvC[c4*4+0], w.x, a);
        a = fmaf(xvC[c4*4+1], w.y, a);
        a = fmaf(xvC[c4*4+2], w.z, a);
        a = fmaf(xvC[c4*4+3], w.w, a);
      }
      szb[((size_t)(bi*64+d0z+jj))*SEQL + l0 + lane] = a * sigmoid_f(a);
    }
  }
  __syncthreads();

  // ---- depthwise conv1d (4 taps) + silu ----
  #pragma unroll
  for (int jj=0;jj<4;++jj){
    int d = tyu*4 + jj;
    float4 w = *(const float4*)(cw + d*4);
    float a = xm[d][lane]*w.x + xm[d][lane+1]*w.y
            + xm[d][lane+2]*w.z + xm[d][lane+3]*w.w + cb[d];
    float s = a * sigmoid_f(a);
    xtT[d][lane] = s;
    xm2[((size_t)(bi*64+d))*SEQL + l0 + lane] = s;
  }
  __syncthreads();

  // ---- x_proj ----
  {
    float xv[64];
    #pragma unroll
    for (int c=0;c<64;++c) xv[c] = xtT[c][lane];
    for (int j=tyu; j<66; j+=16){
      const float4* wr = (const float4*)(Wxp + j*64);
      float a = 0.0f;
      #pragma unroll
      for (int c4=0;c4<16;++c4){
        float4 w = wr[c4];
        a = fmaf(xv[c4*4+0], w.x, a);
        a = fmaf(xv[c4*4+1], w.y, a);
        a = fmaf(xv[c4*4+2], w.z, a);
        a = fmaf(xv[c4*4+3], w.w, a);
      }
      xd[lane][j] = a;
    }
  }
  __syncthreads();

  // ---- dt_proj + softplus, B/C permuted store, xbT copy ----
  {
    float dt0 = xd[lane][0], dt1 = xd[lane][1];
    #pragma unroll
    for (int k=0;k<4;++k){
      int d2 = tyu*4 + k;
      float2 wd = *(const float2*)(Wdt + d2*2);
      float v = dt0*wd.x + dt1*wd.y + bdt[d2];
      float sp = fmaxf(v,0.0f) + log1pf(expf(-fabsf(v)));
      dlt[((size_t)(bi*64+d2))*SEQL + l0 + lane] = sp;
      xm[d2][lane] = sp;                      // dl[d][tok] (aliases xm)
    }
    const int which = tyu >> 3, gq = tyu & 7;
    float* dst = which ? Cm : Bm;
    size_t base = ((size_t)bi*SEQL + l0 + lane)*32 + gq*4;
    const int s2 = 2 + which*32;
    float4 f0;
    f0.x = xd[lane][s2+gq+ 0]; f0.y = xd[lane][s2+gq+ 8];
    f0.z = xd[lane][s2+gq+16]; f0.w = xd[lane][s2+gq+24];
    *(float4*)(dst + base) = f0;
    if (!which){                               // B transposed: xbT[n][tok]
      xbT[gq     ][lane] = f0.x;
      xbT[gq +  8][lane] = f0.y;
      xbT[gq + 16][lane] = f0.z;
      xbT[gq + 24][lane] = f0.w;
    }
  }
  __syncthreads();

  // ---- scan pass 1: ds_read_b128 over t; cA/cH [bd][chunk][n] coalesced ----
  {
    const int d  = tid >> 4;
    const int gg = tid & 15;
    const int chunk = blockIdx.x & 63;
    const int bd = bi*64 + d;
    float Av0 = -expf(A_log[d*32 + gg     ]) * L2E;
    float Av1 = -expf(A_log[d*32 + gg + 16]) * L2E;
    float h0=0.0f, h1=0.0f, aP0=1.0f, aP1=1.0f;
    #pragma unroll 2
    for (int t0=0;t0<64;t0+=4){
      float4 dl4 = *(const float4*)&xm [d    ][t0];
      float4 xs4 = *(const float4*)&xtT[d    ][t0];
      float4 b04 = *(const float4*)&xbT[gg   ][t0];
      float4 b14 = *(const float4*)&xbT[gg+16][t0];
      #pragma unroll
      for (int k=0;k<4;++k){
        float dlv = (k==0)? dl4.x : (k==1)? dl4.y : (k==2)? dl4.z : dl4.w;
        float xsv = (k==0)? xs4.x : (k==1)? xs4.y : (k==2)? xs4.z : xs4.w;
        float bv0 = (k==0)? b04.x : (k==1)? b04.y : (k==2)? b04.z : b04.w;
        float bv1 = (k==0)? b14.x : (k==1)? b14.y : (k==2)? b14.z : b14.w;
        float m  = dlv * xsv;
        float a0 = FAST_EXP2(dlv*Av0);
        float a1 = FAST_EXP2(dlv*Av1);
        h0 = fmaf(a0, h0, m*bv0);  aP0 *= a0;
        h1 = fmaf(a1, h1, m*bv1);  aP1 *= a1;
      }
    }
    size_t base = ((size_t)bd*64 + chunk)*32;
    cA[base + gg] = aP0; cA[base + gg + 16] = aP1;
    cH[base + gg] = h0;  cH[base + gg + 16] = h1;
  }
}

// ---- scan pass 2 (R5 known-good): 8 lanes/chunk x 4 n-chains/lane,
//      inline prefix, buffered 64B-line yt stores. ----
__global__ __launch_bounds__(256) void scan_p2(const float* __restrict__ dlt,
    const float* __restrict__ xssm, const float* __restrict__ Bm,
    const float* __restrict__ Cm, const float* __restrict__ A_log,
    const float* __restrict__ Dp, const float* __restrict__ sz,
    const float* __restrict__ cA, const float* __restrict__ cHs,
    float* __restrict__ yt)
{
  __shared__ float pre[32][34];
  const int tid = threadIdx.x;
  const int grp = blockIdx.x & 1;            // half: chunks grp*32 .. +31
  const int bd  = blockIdx.x >> 1;
  const int b = bd >> 6, d = bd & 63;
  const int c0 = grp << 5;

  if (tid < 32){
    const float* pa = cA  + (size_t)bd*2048 + tid;   // [bd][chunk][n], n=tid
    const float* ph = cHs + (size_t)bd*2048 + tid;
    float hrun = 0.0f;
    if (grp){
      #pragma unroll 4
      for (int c=0;c<32;++c)
        hrun = fmaf(pa[c*32], hrun, ph[c*32]);
    }
    #pragma unroll 4
    for (int k=0;k<32;++k){
      pre[tid][k] = hrun;
      hrun = fmaf(pa[(c0+k)*32], hrun, ph[(c0+k)*32]);
    }
  }
  __syncthreads();

  const int lc = tid >> 3, gg = tid & 7;
  const int chunk = c0 + lc;
  const int l0 = chunk << 6;
  const float Dv = Dp[d];
  float Av2[4], h[4];
  #pragma unroll
  for (int j=0;j<4;++j){
    Av2[j] = -expf(A_log[d*32 + gg + 8*j]) * L2E;
    h[j] = pre[gg + 8*j][lc];
  }
  const float* del = dlt  + (size_t)bd*SEQL + l0;
  const float* xp  = xssm + (size_t)bd*SEQL + l0;
  const float* szp = sz   + (size_t)bd*SEQL + l0;
  const float* Bp  = Bm + ((size_t)b*SEQL + l0)*32 + gg*4;
  const float* Cp  = Cm + ((size_t)b*SEQL + l0)*32 + gg*4;
  float* yp = yt + (size_t)bd*SEQL + l0;

  for (int i0=0;i0<64;i0+=16){
    float4 y4[4];
    #pragma unroll
    for (int s=0;s<4;++s){
      const int ib = i0 + s*4;
      float4 d4 = *(const float4*)(del+ib);
      float4 x4 = *(const float4*)(xp +ib);
      float4 s4 = *(const float4*)(szp+ib);
      #pragma unroll
      for (int t=0;t<4;++t){
        float dl = (t==0)? d4.x : (t==1)? d4.y : (t==2)? d4.z : d4.w;
        float xl = (t==0)? x4.x : (t==1)? x4.y : (t==2)? x4.z : x4.w;
        float sl = (t==0)? s4.x : (t==1)? s4.y : (t==2)? s4.z : s4.w;
        float4 bv = *(const float4*)(Bp + (ib+t)*32);
        float4 cv = *(const float4*)(Cp + (ib+t)*32);
        float a0 = FAST_EXP2(dl*Av2[0]); h[0] = fmaf(a0, h[0], dl*bv.x*xl);
        float a1 = FAST_EXP2(dl*Av2[1]); h[1] = fmaf(a1, h[1], dl*bv.y*xl);
        float a2 = FAST_EXP2(dl*Av2[2]); h[2] = fmaf(a2, h[2], dl*bv.z*xl);
        float a3 = FAST_EXP2(dl*Av2[3]); h[3] = fmaf(a3, h[3], dl*bv.w*xl);
        float v = fmaf(h[3], cv.w, fmaf(h[2], cv.z, fmaf(h[1], cv.y, h[0]*cv.x)));
        v += __shfl_xor(v,1); v += __shfl_xor(v,2); v += __shfl_xor(v,4);
        float yv = fmaf(xl, Dv, v) * sl;
        if      (t==0) y4[s].x = yv;
        else if (t==1) y4[s].y = yv;
        else if (t==2) y4[s].z = yv;
        else           y4[s].w = yv;
      }
    }
    if (gg < 4){
      float4 w = (gg==0) ? y4[0] : (gg==1) ? y4[1] : (gg==2) ? y4[2] : y4[3];
      *(float4*)(yp + i0 + gg*4) = w;
    }
  }
}

// ---------------- out_proj (64->32) into (b,c,l) = NCHW image --------------
// Weight rows uniform via readfirstlane + float4 -> s_load traffic.
__global__ __launch_bounds__(512) void outproj_k(const float* __restrict__ yt,
    const float* __restrict__ Wout, float* __restrict__ ym)
{
  __shared__ float ys[64][67];
  const int tid = threadIdx.x, lane = tid & 63, ty = tid >> 6;
  const int tyu = __builtin_amdgcn_readfirstlane(ty);
  const int bi = blockIdx.x >> 6;
  const int l0 = (blockIdx.x & 63) << 6;
  for (int r=ty; r<64; r+=8)
    ys[lane][r] = yt[((size_t)(bi*64+r))*SEQL + l0 + lane];
  __syncthreads();
  float yv[64];
  #pragma unroll
  for (int c=0;c<64;++c) yv[c] = ys[lane][c];
  #pragma unroll
  for (int jj=0;jj<4;++jj){
    int j = tyu*4 + jj;
    const float4* wr = (const float4*)(Wout + j*64);
    float acc = 0.0f;
    #pragma unroll
    for (int c4=0;c4<16;++c4){
      float4 w = wr[c4];
      acc = fmaf(yv[c4*4+0], w.x, acc);
      acc = fmaf(yv[c4*4+1], w.y, acc);
      acc = fmaf(yv[c4*4+2], w.z, acc);
      acc = fmaf(yv[c4*4+3], w.w, acc);
    }
    ym[((size_t)(bi*32+j))*SEQL + l0 + lane] = acc;
  }
}

extern "C" void kernel_launch(void* const* d_in, const int* in_sizes, int n_in,
                              void* d_out, int out_size, void* d_ws, size_t ws_size,
                              hipStream_t stream) {
  const float* x        = (const float*)d_in[0];
  const float* conv1_w  = (const float*)d_in[1];
  const float* conv1_b  = (const float*)d_in[2];
  const float* conv2_w  = (const float*)d_in[3];
  const float* conv2_b  = (const float*)d_in[4];
  const float* ln_g     = (const float*)d_in[5];
  const float* ln_b     = (const float*)d_in[6];
  const float* in_proj_w= (const float*)d_in[7];
  const float* conv1d_w = (const float*)d_in[8];
  const float* conv1d_b = (const float*)d_in[9];
  const float* x_proj_w = (const float*)d_in[10];
  const float* dt_proj_w= (const float*)d_in[11];
  const float* dt_proj_b= (const float*)d_in[12];
  const float* A_log    = (const float*)d_in[13];
  const float* Dp       = (const float*)d_in[14];
  const float* out_proj_w=(const float*)d_in[15];
  const float* smooth_w = (const float*)d_in[16];
  const float* smooth_b = (const float*)d_in[17];
  float* out = (float*)d_out;

  float* ws = (float*)d_ws;
  float* t      = ws;                 // (4,64,64,64)  1048576  (free after conv2)
  float* x2     = t      + 1048576;   // (4,32,4096)    524288
  float* xm2    = x2     + 524288;    // (4,64,4096)   1048576
  float* szb    = xm2    + 1048576;   // (4,64,4096)   1048576
  float* dlt    = szb    + 1048576;   // (4,64,4096)   1048576
  float* Bmat   = dlt    + 1048576;   // (4,4096,32)    524288
  float* Cmat   = Bmat   + 524288;    // (4,4096,32)    524288
  float* yt     = Cmat   + 524288;    // (4,64,4096)   1048576
  float* ym     = yt     + 1048576;   // (4,32,4096)    524288
  float* cA     = t;                  // (256,64,32)    524288 (aliases t)
  float* cH     = t + 524288;         // (256,64,32)    524288 (aliases t)

  conv3x3_k<32,64,8,true ,false><<<dim3(64,2,4), 256, 0, stream>>>(x,  conv1_w, conv1_b, nullptr, t);
  conv3x3_k<64,32,4,false,true ><<<dim3(64,2,4), 256, 0, stream>>>(t,  conv2_w, conv2_b, x,       x2);
  mamba_in_k  <<<256, 1024, 0, stream>>>(x2, ln_g, ln_b, in_proj_w, conv1d_w, conv1d_b,
                                         x_proj_w, dt_proj_w, dt_proj_b, A_log,
                                         xm2, szb, dlt, Bmat, Cmat, cA, cH);
  scan_p2     <<<512, 256, 0, stream>>>(dlt, xm2, Bmat, Cmat, A_log, Dp, szb, cA, cH, yt);
  outproj_k   <<<256, 512, 0, stream>>>(yt, out_proj_w, ym);
  conv3x3_k<32,32,4,false,false><<<dim3(64,2,4), 256, 0, stream>>>(ym, smooth_w, smooth_b, nullptr, out);
}

// Round 11
// 187.284 us; speedup vs baseline: 1.5738x; 1.5738x over previous
//
#include <hip/hip_runtime.h>
#include <math.h>

#define SEQL 4096
#define L2E 1.44269504088896340736f

#if defined(__has_builtin)
#if __has_builtin(__builtin_amdgcn_exp2f)
#define FAST_EXP2(x) __builtin_amdgcn_exp2f(x)
#endif
#endif
#ifndef FAST_EXP2
#define FAST_EXP2(x) exp2f(x)
#endif

__device__ __forceinline__ float sigmoid_f(float x){ return 1.0f/(1.0f+expf(-x)); }

// ---------------- conv 3x3, pad 1, 64x64 image (v1 skeleton, COG=2) ---------
// v1 reduction structure (best measured: time tracked waves/CU across
// v1/v3/v4/v5, all latency-bound at VALUBusy<=12%). COG 4->2 halves LDS
// (26.5->19.7KB) and acc VGPRs, doubling blocks: conv1 8 blocks/CU =
// 32 waves/CU (8x19.7KB = 157.5KB fits); conv2/smooth 4 blocks/CU.
template<int CI, int CO, int COG, bool RELU, bool RES>
__global__ __launch_bounds__(256) void conv3x3_k(const float* __restrict__ in,
    const float* __restrict__ wgt, const float* __restrict__ bias,
    const float* __restrict__ res, float* __restrict__ out)
{
  constexpr int CIT = CI/4;
  __shared__ float tin[4][2][6][72];
  __shared__ float red[3][4][COG][66];
  const int tid  = threadIdx.x;
  const int lane = tid & 63;
  const int ty   = tid >> 6;
  const int tyu  = __builtin_amdgcn_readfirstlane(ty);
  const int h0   = blockIdx.x * 4;
  const int co0  = blockIdx.y * COG;
  const int b    = blockIdx.z;

  if (lane < 24){
    int cl = lane / 12, rem = lane % 12, r = rem >> 1, side = rem & 1;
    tin[ty][cl][r][side ? 68 : 3] = 0.0f;
  }

  float acc[4][COG];
  #pragma unroll
  for (int rr=0;rr<4;++rr)
    #pragma unroll
    for (int u=0;u<COG;++u) acc[rr][u] = 0.0f;

  const int ci0 = tyu*CIT;
  for (int cig = ci0; cig < ci0 + CIT; cig += 2){
    #pragma unroll
    for (int k=0;k<3;++k){
      int idx4 = lane + (k<<6);
      int row  = idx4 >> 4;
      int cl = row/6, r = row - cl*6;
      int w4 = (idx4 & 15) << 2;
      int h  = h0 - 1 + r;
      float4 v = make_float4(0.f,0.f,0.f,0.f);
      if (h>=0 && h<64)
        v = *(const float4*)(in + ((size_t)(b*CI+cig+cl)*64 + h)*64 + w4);
      *(float4*)&tin[ty][cl][r][4+w4] = v;
    }
    #pragma unroll
    for (int cl=0; cl<2; ++cl){
      float rv[6][3];
      #pragma unroll
      for (int r=0;r<6;++r)
        #pragma unroll
        for (int c=0;c<3;++c)
          rv[r][c] = tin[ty][cl][r][3+lane+c];
      #pragma unroll
      for (int u=0;u<COG;++u){
        const float* wp = wgt + ((size_t)(co0+u)*CI + cig + cl)*9;
        #pragma unroll
        for (int rr=0;rr<4;++rr)
          #pragma unroll
          for (int j=0;j<3;++j){
            acc[rr][u] = fmaf(rv[rr+j][0], wp[3*j+0], acc[rr][u]);
            acc[rr][u] = fmaf(rv[rr+j][1], wp[3*j+1], acc[rr][u]);
            acc[rr][u] = fmaf(rv[rr+j][2], wp[3*j+2], acc[rr][u]);
          }
      }
    }
  }
  if (ty > 0){
    #pragma unroll
    for (int rr=0;rr<4;++rr)
      #pragma unroll
      for (int u=0;u<COG;++u) red[ty-1][rr][u][lane] = acc[rr][u];
  }
  __syncthreads();
  if (ty == 0){
    #pragma unroll
    for (int rr=0;rr<4;++rr)
      #pragma unroll
      for (int u=0;u<COG;++u){
        float s = acc[rr][u] + red[0][rr][u][lane] + red[1][rr][u][lane]
                + red[2][rr][u][lane] + bias[co0+u];
        size_t ob = ((size_t)(b*CO+co0+u)*64 + h0+rr)*64 + lane;
        if constexpr (RES)  s += res[ob];
        if constexpr (RELU) s = fmaxf(s, 0.0f);
        out[ob] = s;
      }
  }
}

// ---- fused mamba front + scan pass 1 (64-token tiles, 1024-thread blocks).
//      (R5 known-good: uniform weight s_loads, transposed scan LDS, coalesced
//      cA/cH [bd][chunk][n].)
__global__ __launch_bounds__(1024, 4) void mamba_in_k(const float* __restrict__ x2,
    const float* __restrict__ g, const float* __restrict__ be,
    const float* __restrict__ Wip, const float* __restrict__ cw,
    const float* __restrict__ cb, const float* __restrict__ Wxp,
    const float* __restrict__ Wdt, const float* __restrict__ bdt,
    const float* __restrict__ A_log,
    float* __restrict__ xm2, float* __restrict__ szb, float* __restrict__ dlt,
    float* __restrict__ Bm, float* __restrict__ Cm,
    float* __restrict__ cA, float* __restrict__ cH)
{
  __shared__ __align__(16) float xn[68][37];   // LN'd tokens; later aliased xbT[32][68]
  __shared__ __align__(16) float xm[64][68];   // in_proj xm half [d][t]; later dl[d][tok]
  __shared__ __align__(16) float xtT[64][68];  // silu(conv) TRANSPOSED [d][tok]
  __shared__ __align__(16) float xd[64][67];   // x_dbl [tok][j]
  float (*xbT)[68] = reinterpret_cast<float(*)[68]>(&xn[0][0]); // B [n][tok], aliases xn
  const int tid = threadIdx.x, lane = tid & 63, ty = tid >> 6;  // ty 0..15
  const int tyu = __builtin_amdgcn_readfirstlane(ty);
  const int bi = blockIdx.x >> 6;
  const int l0 = (blockIdx.x & 63) << 6;

  // ---- LayerNorm: 67 rows (64 + 3 halo), 8 lanes/row, shfl-tree reduce ----
  {
    const int row = tid >> 3, sub = tid & 7;
    if (row < 67){
      const int tok = l0 - 3 + row;
      const int c0 = sub << 2;
      if (tok >= 0){
        float4 f = *(const float4*)(x2 + (size_t)bi*131072 + (size_t)tok*32 + c0);
        float s = (f.x+f.y)+(f.z+f.w);
        s += __shfl_xor(s,1); s += __shfl_xor(s,2); s += __shfl_xor(s,4);
        const float mu = s * 0.03125f;
        float dx=f.x-mu, dy=f.y-mu, dz=f.z-mu, dw=f.w-mu;
        float q = (dx*dx+dy*dy)+(dz*dz+dw*dw);
        q += __shfl_xor(q,1); q += __shfl_xor(q,2); q += __shfl_xor(q,4);
        const float rstd = 1.0f/sqrtf(q*0.03125f + 1e-5f);
        float4 gv = *(const float4*)(g  + c0);
        float4 bv = *(const float4*)(be + c0);
        xn[row][c0+0] = dx*rstd*gv.x + bv.x;
        xn[row][c0+1] = dy*rstd*gv.y + bv.y;
        xn[row][c0+2] = dz*rstd*gv.z + bv.z;
        xn[row][c0+3] = dw*rstd*gv.w + bv.w;
      } else {
        xn[row][c0+0]=0.0f; xn[row][c0+1]=0.0f;
        xn[row][c0+2]=0.0f; xn[row][c0+3]=0.0f;
      }
    }
  }
  __syncthreads();

  // ---- in_proj ----
  if (ty < 8){
    const int d0 = tyu*8;
    float xvA[32];
    #pragma unroll
    for (int c=0;c<32;++c) xvA[c] = xn[lane][c];
    #pragma unroll
    for (int jj=0;jj<8;++jj){
      const float4* wr = (const float4*)(Wip + (d0+jj)*32);
      float a = 0.0f;
      #pragma unroll
      for (int c4=0;c4<8;++c4){
        float4 w = wr[c4];
        a = fmaf(xvA[c4*4+0], w.x, a);
        a = fmaf(xvA[c4*4+1], w.y, a);
        a = fmaf(xvA[c4*4+2], w.z, a);
        a = fmaf(xvA[c4*4+3], w.w, a);
      }
      xm[d0+jj][lane] = a;
    }
    if (lane < 3){
      float xvB[32];
      #pragma unroll
      for (int c=0;c<32;++c) xvB[c] = xn[64+lane][c];
      #pragma unroll
      for (int jj=0;jj<8;++jj){
        const float4* wr = (const float4*)(Wip + (d0+jj)*32);
        float a = 0.0f;
        #pragma unroll
        for (int c4=0;c4<8;++c4){
          float4 w = wr[c4];
          a = fmaf(xvB[c4*4+0], w.x, a);
          a = fmaf(xvB[c4*4+1], w.y, a);
          a = fmaf(xvB[c4*4+2], w.z, a);
          a = fmaf(xvB[c4*4+3], w.w, a);
        }
        xm[d0+jj][64+lane] = a;
      }
    }
  } else {
    const int d0z = (tyu-8)*8;
    float xvC[32];
    #pragma unroll
    for (int c=0;c<32;++c) xvC[c] = xn[lane+3][c];
    #pragma unroll
    for (int jj=0;jj<8;++jj){
      const float4* wr = (const float4*)(Wip + (64+d0z+jj)*32);
      float a = 0.0f;
      #pragma unroll
      for (int c4=0;c4<8;++c4){
        float4 w = wr[c4];
        a = fmaf(xvC[c4*4+0], w.x, a);
        a = fmaf(xvC[c4*4+1], w.y, a);
        a = fmaf(xvC[c4*4+2], w.z, a);
        a = fmaf(xvC[c4*4+3], w.w, a);
      }
      szb[((size_t)(bi*64+d0z+jj))*SEQL + l0 + lane] = a * sigmoid_f(a);
    }
  }
  __syncthreads();

  // ---- depthwise conv1d (4 taps) + silu ----
  #pragma unroll
  for (int jj=0;jj<4;++jj){
    int d = tyu*4 + jj;
    float4 w = *(const float4*)(cw + d*4);
    float a = xm[d][lane]*w.x + xm[d][lane+1]*w.y
            + xm[d][lane+2]*w.z + xm[d][lane+3]*w.w + cb[d];
    float s = a * sigmoid_f(a);
    xtT[d][lane] = s;
    xm2[((size_t)(bi*64+d))*SEQL + l0 + lane] = s;
  }
  __syncthreads();

  // ---- x_proj ----
  {
    float xv[64];
    #pragma unroll
    for (int c=0;c<64;++c) xv[c] = xtT[c][lane];
    for (int j=tyu; j<66; j+=16){
      const float4* wr = (const float4*)(Wxp + j*64);
      float a = 0.0f;
      #pragma unroll
      for (int c4=0;c4<16;++c4){
        float4 w = wr[c4];
        a = fmaf(xv[c4*4+0], w.x, a);
        a = fmaf(xv[c4*4+1], w.y, a);
        a = fmaf(xv[c4*4+2], w.z, a);
        a = fmaf(xv[c4*4+3], w.w, a);
      }
      xd[lane][j] = a;
    }
  }
  __syncthreads();

  // ---- dt_proj + softplus, B/C permuted store, xbT copy ----
  {
    float dt0 = xd[lane][0], dt1 = xd[lane][1];
    #pragma unroll
    for (int k=0;k<4;++k){
      int d2 = tyu*4 + k;
      float2 wd = *(const float2*)(Wdt + d2*2);
      float v = dt0*wd.x + dt1*wd.y + bdt[d2];
      float sp = fmaxf(v,0.0f) + log1pf(expf(-fabsf(v)));
      dlt[((size_t)(bi*64+d2))*SEQL + l0 + lane] = sp;
      xm[d2][lane] = sp;                      // dl[d][tok] (aliases xm)
    }
    const int which = tyu >> 3, gq = tyu & 7;
    float* dst = which ? Cm : Bm;
    size_t base = ((size_t)bi*SEQL + l0 + lane)*32 + gq*4;
    const int s2 = 2 + which*32;
    float4 f0;
    f0.x = xd[lane][s2+gq+ 0]; f0.y = xd[lane][s2+gq+ 8];
    f0.z = xd[lane][s2+gq+16]; f0.w = xd[lane][s2+gq+24];
    *(float4*)(dst + base) = f0;
    if (!which){                               // B transposed: xbT[n][tok]
      xbT[gq     ][lane] = f0.x;
      xbT[gq +  8][lane] = f0.y;
      xbT[gq + 16][lane] = f0.z;
      xbT[gq + 24][lane] = f0.w;
    }
  }
  __syncthreads();

  // ---- scan pass 1: ds_read_b128 over t; cA/cH [bd][chunk][n] coalesced ----
  {
    const int d  = tid >> 4;
    const int gg = tid & 15;
    const int chunk = blockIdx.x & 63;
    const int bd = bi*64 + d;
    float Av0 = -expf(A_log[d*32 + gg     ]) * L2E;
    float Av1 = -expf(A_log[d*32 + gg + 16]) * L2E;
    float h0=0.0f, h1=0.0f, aP0=1.0f, aP1=1.0f;
    #pragma unroll 2
    for (int t0=0;t0<64;t0+=4){
      float4 dl4 = *(const float4*)&xm [d    ][t0];
      float4 xs4 = *(const float4*)&xtT[d    ][t0];
      float4 b04 = *(const float4*)&xbT[gg   ][t0];
      float4 b14 = *(const float4*)&xbT[gg+16][t0];
      #pragma unroll
      for (int k=0;k<4;++k){
        float dlv = (k==0)? dl4.x : (k==1)? dl4.y : (k==2)? dl4.z : dl4.w;
        float xsv = (k==0)? xs4.x : (k==1)? xs4.y : (k==2)? xs4.z : xs4.w;
        float bv0 = (k==0)? b04.x : (k==1)? b04.y : (k==2)? b04.z : b04.w;
        float bv1 = (k==0)? b14.x : (k==1)? b14.y : (k==2)? b14.z : b14.w;
        float m  = dlv * xsv;
        float a0 = FAST_EXP2(dlv*Av0);
        float a1 = FAST_EXP2(dlv*Av1);
        h0 = fmaf(a0, h0, m*bv0);  aP0 *= a0;
        h1 = fmaf(a1, h1, m*bv1);  aP1 *= a1;
      }
    }
    size_t base = ((size_t)bd*64 + chunk)*32;
    cA[base + gg] = aP0; cA[base + gg + 16] = aP1;
    cH[base + gg] = h0;  cH[base + gg + 16] = h1;
  }
}

// ---- scan pass 2 (R5 known-good): 8 lanes/chunk x 4 n-chains/lane,
//      inline prefix, buffered 64B-line yt stores. ----
__global__ __launch_bounds__(256) void scan_p2(const float* __restrict__ dlt,
    const float* __restrict__ xssm, const float* __restrict__ Bm,
    const float* __restrict__ Cm, const float* __restrict__ A_log,
    const float* __restrict__ Dp, const float* __restrict__ sz,
    const float* __restrict__ cA, const float* __restrict__ cHs,
    float* __restrict__ yt)
{
  __shared__ float pre[32][34];
  const int tid = threadIdx.x;
  const int grp = blockIdx.x & 1;            // half: chunks grp*32 .. +31
  const int bd  = blockIdx.x >> 1;
  const int b = bd >> 6, d = bd & 63;
  const int c0 = grp << 5;

  if (tid < 32){
    const float* pa = cA  + (size_t)bd*2048 + tid;   // [bd][chunk][n], n=tid
    const float* ph = cHs + (size_t)bd*2048 + tid;
    float hrun = 0.0f;
    if (grp){
      #pragma unroll 4
      for (int c=0;c<32;++c)
        hrun = fmaf(pa[c*32], hrun, ph[c*32]);
    }
    #pragma unroll 4
    for (int k=0;k<32;++k){
      pre[tid][k] = hrun;
      hrun = fmaf(pa[(c0+k)*32], hrun, ph[(c0+k)*32]);
    }
  }
  __syncthreads();

  const int lc = tid >> 3, gg = tid & 7;
  const int chunk = c0 + lc;
  const int l0 = chunk << 6;
  const float Dv = Dp[d];
  float Av2[4], h[4];
  #pragma unroll
  for (int j=0;j<4;++j){
    Av2[j] = -expf(A_log[d*32 + gg + 8*j]) * L2E;
    h[j] = pre[gg + 8*j][lc];
  }
  const float* del = dlt  + (size_t)bd*SEQL + l0;
  const float* xp  = xssm + (size_t)bd*SEQL + l0;
  const float* szp = sz   + (size_t)bd*SEQL + l0;
  const float* Bp  = Bm + ((size_t)b*SEQL + l0)*32 + gg*4;
  const float* Cp  = Cm + ((size_t)b*SEQL + l0)*32 + gg*4;
  float* yp = yt + (size_t)bd*SEQL + l0;

  for (int i0=0;i0<64;i0+=16){
    float4 y4[4];
    #pragma unroll
    for (int s=0;s<4;++s){
      const int ib = i0 + s*4;
      float4 d4 = *(const float4*)(del+ib);
      float4 x4 = *(const float4*)(xp +ib);
      float4 s4 = *(const float4*)(szp+ib);
      #pragma unroll
      for (int t=0;t<4;++t){
        float dl = (t==0)? d4.x : (t==1)? d4.y : (t==2)? d4.z : d4.w;
        float xl = (t==0)? x4.x : (t==1)? x4.y : (t==2)? x4.z : x4.w;
        float sl = (t==0)? s4.x : (t==1)? s4.y : (t==2)? s4.z : s4.w;
        float4 bv = *(const float4*)(Bp + (ib+t)*32);
        float4 cv = *(const float4*)(Cp + (ib+t)*32);
        float a0 = FAST_EXP2(dl*Av2[0]); h[0] = fmaf(a0, h[0], dl*bv.x*xl);
        float a1 = FAST_EXP2(dl*Av2[1]); h[1] = fmaf(a1, h[1], dl*bv.y*xl);
        float a2 = FAST_EXP2(dl*Av2[2]); h[2] = fmaf(a2, h[2], dl*bv.z*xl);
        float a3 = FAST_EXP2(dl*Av2[3]); h[3] = fmaf(a3, h[3], dl*bv.w*xl);
        float v = fmaf(h[3], cv.w, fmaf(h[2], cv.z, fmaf(h[1], cv.y, h[0]*cv.x)));
        v += __shfl_xor(v,1); v += __shfl_xor(v,2); v += __shfl_xor(v,4);
        float yv = fmaf(xl, Dv, v) * sl;
        if      (t==0) y4[s].x = yv;
        else if (t==1) y4[s].y = yv;
        else if (t==2) y4[s].z = yv;
        else           y4[s].w = yv;
      }
    }
    if (gg < 4){
      float4 w = (gg==0) ? y4[0] : (gg==1) ? y4[1] : (gg==2) ? y4[2] : y4[3];
      *(float4*)(yp + i0 + gg*4) = w;
    }
  }
}

// ---------------- out_proj (64->32) into (b,c,l) = NCHW image --------------
// Weight rows uniform via readfirstlane + float4 -> s_load traffic.
__global__ __launch_bounds__(512) void outproj_k(const float* __restrict__ yt,
    const float* __restrict__ Wout, float* __restrict__ ym)
{
  __shared__ float ys[64][67];
  const int tid = threadIdx.x, lane = tid & 63, ty = tid >> 6;
  const int tyu = __builtin_amdgcn_readfirstlane(ty);
  const int bi = blockIdx.x >> 6;
  const int l0 = (blockIdx.x & 63) << 6;
  for (int r=ty; r<64; r+=8)
    ys[lane][r] = yt[((size_t)(bi*64+r))*SEQL + l0 + lane];
  __syncthreads();
  float yv[64];
  #pragma unroll
  for (int c=0;c<64;++c) yv[c] = ys[lane][c];
  #pragma unroll
  for (int jj=0;jj<4;++jj){
    int j = tyu*4 + jj;
    const float4* wr = (const float4*)(Wout + j*64);
    float acc = 0.0f;
    #pragma unroll
    for (int c4=0;c4<16;++c4){
      float4 w = wr[c4];
      acc = fmaf(yv[c4*4+0], w.x, acc);
      acc = fmaf(yv[c4*4+1], w.y, acc);
      acc = fmaf(yv[c4*4+2], w.z, acc);
      acc = fmaf(yv[c4*4+3], w.w, acc);
    }
    ym[((size_t)(bi*32+j))*SEQL + l0 + lane] = acc;
  }
}

extern "C" void kernel_launch(void* const* d_in, const int* in_sizes, int n_in,
                              void* d_out, int out_size, void* d_ws, size_t ws_size,
                              hipStream_t stream) {
  const float* x        = (const float*)d_in[0];
  const float* conv1_w  = (const float*)d_in[1];
  const float* conv1_b  = (const float*)d_in[2];
  const float* conv2_w  = (const float*)d_in[3];
  const float* conv2_b  = (const float*)d_in[4];
  const float* ln_g     = (const float*)d_in[5];
  const float* ln_b     = (const float*)d_in[6];
  const float* in_proj_w= (const float*)d_in[7];
  const float* conv1d_w = (const float*)d_in[8];
  const float* conv1d_b = (const float*)d_in[9];
  const float* x_proj_w = (const float*)d_in[10];
  const float* dt_proj_w= (const float*)d_in[11];
  const float* dt_proj_b= (const float*)d_in[12];
  const float* A_log    = (const float*)d_in[13];
  const float* Dp       = (const float*)d_in[14];
  const float* out_proj_w=(const float*)d_in[15];
  const float* smooth_w = (const float*)d_in[16];
  const float* smooth_b = (const float*)d_in[17];
  float* out = (float*)d_out;

  float* ws = (float*)d_ws;
  float* t      = ws;                 // (4,64,64,64)  1048576  (free after conv2)
  float* x2     = t      + 1048576;   // (4,32,4096)    524288
  float* xm2    = x2     + 524288;    // (4,64,4096)   1048576
  float* szb    = xm2    + 1048576;   // (4,64,4096)   1048576
  float* dlt    = szb    + 1048576;   // (4,64,4096)   1048576
  float* Bmat   = dlt    + 1048576;   // (4,4096,32)    524288
  float* Cmat   = Bmat   + 524288;    // (4,4096,32)    524288
  float* yt     = Cmat   + 524288;    // (4,64,4096)   1048576
  float* ym     = yt     + 1048576;   // (4,32,4096)    524288
  float* cA     = t;                  // (256,64,32)    524288 (aliases t)
  float* cH     = t + 524288;         // (256,64,32)    524288 (aliases t)

  conv3x3_k<32,64,2,true ,false><<<dim3(16,32,4), 256, 0, stream>>>(x,  conv1_w, conv1_b, nullptr, t);
  conv3x3_k<64,32,2,false,true ><<<dim3(16,16,4), 256, 0, stream>>>(t,  conv2_w, conv2_b, x,       x2);
  mamba_in_k  <<<256, 1024, 0, stream>>>(x2, ln_g, ln_b, in_proj_w, conv1d_w, conv1d_b,
                                         x_proj_w, dt_proj_w, dt_proj_b, A_log,
                                         xm2, szb, dlt, Bmat, Cmat, cA, cH);
  scan_p2     <<<512, 256, 0, stream>>>(dlt, xm2, Bmat, Cmat, A_log, Dp, szb, cA, cH, yt);
  outproj_k   <<<256, 512, 0, stream>>>(yt, out_proj_w, ym);
  conv3x3_k<32,32,2,false,false><<<dim3(16,16,4), 256, 0, stream>>>(ym, smooth_w, smooth_b, nullptr, out);
}